// Round 1
// baseline (43.014 us; speedup 1.0000x reference)
//
#include <hip/hip_runtime.h>

#define NGRAM 4
#define KDIM 121
#define GDIM 5
#define FEPS 1e-9f
#define NKDIM (NGRAM * KDIM)      // 484
#define GNKDIM (GDIM * NKDIM)     // 2420
#define NCOMBO 81                 // 3^4

__device__ __forceinline__ float pick3(int s, float x0, float x1, float x2) {
    return (s == 0) ? x0 : ((s == 1) ? x1 : x2);
}

__global__ __launch_bounds__(256) void bleu_kernel(
    const float* __restrict__ tc_res,   // [B,1,4,121]
    const float* __restrict__ tc_gts,   // [B,5,4,121]
    const float* __restrict__ l_res,    // [B,1]
    const float* __restrict__ l_gts,    // [B,5]
    float* __restrict__ o_score,        // [B]
    float* __restrict__ o_slist,        // [B,81]
    float* __restrict__ o_judge,        // [B,4,121]
    float* __restrict__ o_sdl,          // [B]
    int B)
{
    const int wave = (blockIdx.x * blockDim.x + threadIdx.x) >> 6;
    const int lane = threadIdx.x & 63;
    if (wave >= B) return;
    const int b = wave;

    const float* res = tc_res + (size_t)b * NKDIM;
    const float* gts = tc_gts + (size_t)b * GNKDIM;
    float* judge = o_judge + (size_t)b * NKDIM;

    // ---- clipped n-gram sums + judge output ----
    float clip[NGRAM];
    #pragma unroll
    for (int n = 0; n < NGRAM; ++n) {
        float part = 0.0f;
        for (int k = lane; k < KDIM; k += 64) {
            const int off = n * KDIM + k;
            const float g = res[off];
            float m = gts[0 * NKDIM + off];
            m = fmaxf(m, gts[1 * NKDIM + off]);
            m = fmaxf(m, gts[2 * NKDIM + off]);
            m = fmaxf(m, gts[3 * NKDIM + off]);
            m = fmaxf(m, gts[4 * NKDIM + off]);
            const float mclip = m + FEPS;   // rounds to m for m>=1, 1e-9 for m==0 (same as JAX f32)
            judge[off] = (g <= mclip) ? 1.0f : 0.0f;
            part += fminf(g, mclip);
        }
        // wave-wide sum (64 lanes)
        #pragma unroll
        for (int s = 1; s < 64; s <<= 1)
            part += __shfl_xor(part, s, 64);
        clip[n] = part;
    }

    // ---- scalar epilogue (redundant on all lanes) ----
    const float l_i = l_res[b];
    float best_d = 1e30f;
    float l_r = 0.0f;
    #pragma unroll
    for (int g = 0; g < GDIM; ++g) {
        float lg = l_gts[(size_t)b * GDIM + g];
        lg = (lg == 0.0f) ? 200.0f : lg;      // LEN_MAX*10
        const float d = fabsf(l_i - lg);
        if (d < best_d) { best_d = d; l_r = lg; }   // strict < -> first argmin
    }

    const float li_e = l_i + FEPS;
    const float und = 1.0f / li_e;
    const float r = (l_r + FEPS) / li_e;
    // In f32, 1.0+1e-9 == 1.0f (matches JAX f32 arithmetic)
    const float lf = __expf(1.0f - fmaxf(1.0f, r)) == 0.0f ? 0.0f : expf(1.0f - fmaxf(1.0f, r));

    const float gf0 = clip[0] * und;
    const float gf1 = clip[1] * und;
    const float gf2 = clip[2] * und;
    const float gf3 = clip[3] * und;

    // channels: 0 = gf, 1 = gf + und, 2 = relu(gf - und)
    const float c00 = gf0, c01 = gf1, c02 = gf2, c03 = gf3;
    const float c10 = gf0 + und, c11 = gf1 + und, c12 = gf2 + und, c13 = gf3 + und;
    const float c20 = fmaxf(gf0 - und, 0.0f);
    const float c21 = fmaxf(gf1 - und, 0.0f);
    const float c22 = fmaxf(gf2 - und, 0.0f);
    const float c23 = fmaxf(gf3 - und, 0.0f);

    const float p_last = c20 * c21 * c22 * c23;
    const float cf_last = lf * sqrtf(sqrtf(p_last));

    for (int c = lane; c < NCOMBO; c += 64) {
        const int i = c / 27;
        const int j = (c / 9) % 3;
        const int kk = (c / 3) % 3;
        const int l = c % 3;
        const float p = pick3(i, c00, c10, c20) *
                        pick3(j, c01, c11, c21) *
                        pick3(kk, c02, c12, c22) *
                        pick3(l, c03, c13, c23);
        const float cf = lf * sqrtf(sqrtf(p));
        o_slist[(size_t)b * NCOMBO + c] = cf - cf_last;
        if (c == 0) o_score[b] = cf;
    }

    if (lane == 0) {
        const float base = gf0 * gf1 * gf2 * gf3;
        // JAX max-tie gradient: w = 1 if r>1, 0.5 if r==1, 0 if r<1
        const float w = (r > 1.0f) ? 1.0f : ((r == 1.0f) ? 0.5f : 0.0f);
        o_sdl[b] = sqrtf(sqrtf(base)) * lf * w * (l_r + FEPS) / (li_e * li_e);
    }
}

extern "C" void kernel_launch(void* const* d_in, const int* in_sizes, int n_in,
                              void* d_out, int out_size, void* d_ws, size_t ws_size,
                              hipStream_t stream) {
    const float* tc_res = (const float*)d_in[0];
    const float* tc_gts = (const float*)d_in[1];
    const float* l_res  = (const float*)d_in[2];
    const float* l_gts  = (const float*)d_in[3];
    const int B = in_sizes[2];   // l_res has B elements

    float* out = (float*)d_out;
    float* o_score = out;
    float* o_slist = o_score + B;
    float* o_judge = o_slist + (size_t)B * NCOMBO;
    float* o_sdl   = o_judge + (size_t)B * NKDIM;

    const int waves_per_block = 4;             // 256 threads
    const int blocks = (B + waves_per_block - 1) / waves_per_block;
    bleu_kernel<<<blocks, 256, 0, stream>>>(tc_res, tc_gts, l_res, l_gts,
                                            o_score, o_slist, o_judge, o_sdl, B);
}

// Round 2
// 41.307 us; speedup vs baseline: 1.0413x; 1.0413x over previous
//
#include <hip/hip_runtime.h>

#define NGRAM 4
#define KDIM 121
#define GDIM 5
#define FEPS 1e-9f
#define NKDIM (NGRAM * KDIM)      // 484 floats per [4,121] block
#define GNKDIM (GDIM * NKDIM)     // 2420
#define NCOMBO 81                 // 3^4
#define NV4 121                   // float4s per 484-float block (484 = 121*4)

__device__ __forceinline__ float pick3(int s, float x0, float x1, float x2) {
    return (s == 0) ? x0 : ((s == 1) ? x1 : x2);
}

__global__ __launch_bounds__(256) void bleu_kernel(
    const float* __restrict__ tc_res,   // [B,1,4,121]
    const float* __restrict__ tc_gts,   // [B,5,4,121]
    const float* __restrict__ l_res,    // [B,1]
    const float* __restrict__ l_gts,    // [B,5]
    float* __restrict__ o_score,        // [B]
    float* __restrict__ o_slist,        // [B,81]
    float* __restrict__ o_judge,        // [B,4,121]
    float* __restrict__ o_sdl,          // [B]
    int B)
{
    const int wave = (blockIdx.x * blockDim.x + threadIdx.x) >> 6;
    const int lane = threadIdx.x & 63;
    if (wave >= B) return;
    const int b = wave;

    // all 16B-aligned: 484 floats = 1936 B = 121*16 B per block/row
    const float4* __restrict__ res4 = (const float4*)(tc_res + (size_t)b * NKDIM);
    const float4* __restrict__ gts4 = (const float4*)(tc_gts + (size_t)b * GNKDIM);
    float4* __restrict__ judge4 = (float4*)(o_judge + (size_t)b * NKDIM);

    float a0 = 0.0f, a1 = 0.0f, a2 = 0.0f, a3 = 0.0f;

    #pragma unroll
    for (int it = 0; it < 2; ++it) {
        const int vi = it * 64 + lane;
        if (vi < NV4) {
            const float4 g  = res4[vi];
            float4 m        = gts4[0 * NV4 + vi];
            const float4 m1 = gts4[1 * NV4 + vi];
            const float4 m2 = gts4[2 * NV4 + vi];
            const float4 m3 = gts4[3 * NV4 + vi];
            const float4 m4 = gts4[4 * NV4 + vi];
            m.x = fmaxf(fmaxf(fmaxf(m.x, m1.x), fmaxf(m2.x, m3.x)), m4.x);
            m.y = fmaxf(fmaxf(fmaxf(m.y, m1.y), fmaxf(m2.y, m3.y)), m4.y);
            m.z = fmaxf(fmaxf(fmaxf(m.z, m1.z), fmaxf(m2.z, m3.z)), m4.z);
            m.w = fmaxf(fmaxf(fmaxf(m.w, m1.w), fmaxf(m2.w, m3.w)), m4.w);
            const float mx = m.x + FEPS, my = m.y + FEPS,
                        mz = m.z + FEPS, mw = m.w + FEPS;

            float4 j;
            j.x = (g.x <= mx) ? 1.0f : 0.0f;
            j.y = (g.y <= my) ? 1.0f : 0.0f;
            j.z = (g.z <= mz) ? 1.0f : 0.0f;
            j.w = (g.w <= mw) ? 1.0f : 0.0f;
            judge4[vi] = j;

            const float cx = fminf(g.x, mx);
            const float cy = fminf(g.y, my);
            const float cz = fminf(g.z, mz);
            const float cw = fminf(g.w, mw);

            const int idx = vi * 4;
            const int n0 = (idx >= KDIM) + (idx >= 2 * KDIM) + (idx >= 3 * KDIM);
            const int n3 = (idx + 3 >= KDIM) + (idx + 3 >= 2 * KDIM) + (idx + 3 >= 3 * KDIM);
            if (n0 == n3) {
                // whole float4 in one n-row (61 of 64 lanes)
                const float s = (cx + cy) + (cz + cw);
                a0 += (n0 == 0) ? s : 0.0f;
                a1 += (n0 == 1) ? s : 0.0f;
                a2 += (n0 == 2) ? s : 0.0f;
                a3 += (n0 == 3) ? s : 0.0f;
            } else {
                // boundary-straddling float4 (vi = 30, 60, 90)
                const float ce[4] = { cx, cy, cz, cw };
                #pragma unroll
                for (int e = 0; e < 4; ++e) {
                    const int ie = idx + e;
                    const int ne = (ie >= KDIM) + (ie >= 2 * KDIM) + (ie >= 3 * KDIM);
                    const float v = ce[e];
                    a0 += (ne == 0) ? v : 0.0f;
                    a1 += (ne == 1) ? v : 0.0f;
                    a2 += (ne == 2) ? v : 0.0f;
                    a3 += (ne == 3) ? v : 0.0f;
                }
            }
        }
    }

    // wave-wide sums (64 lanes)
    #pragma unroll
    for (int s = 1; s < 64; s <<= 1) {
        a0 += __shfl_xor(a0, s, 64);
        a1 += __shfl_xor(a1, s, 64);
        a2 += __shfl_xor(a2, s, 64);
        a3 += __shfl_xor(a3, s, 64);
    }

    // ---- scalar epilogue (redundant on all lanes) ----
    const float l_i = l_res[b];
    float best_d = 1e30f;
    float l_r = 0.0f;
    #pragma unroll
    for (int g = 0; g < GDIM; ++g) {
        float lg = l_gts[(size_t)b * GDIM + g];
        lg = (lg == 0.0f) ? 200.0f : lg;      // LEN_MAX*10
        const float d = fabsf(l_i - lg);
        if (d < best_d) { best_d = d; l_r = lg; }   // strict < -> first argmin
    }

    const float li_e = l_i + FEPS;
    const float und = 1.0f / li_e;
    const float r = (l_r + FEPS) / li_e;
    // In f32, 1.0+1e-9 == 1.0f (matches JAX f32 arithmetic)
    const float lf = expf(1.0f - fmaxf(1.0f, r));

    const float gf0 = a0 * und;
    const float gf1 = a1 * und;
    const float gf2 = a2 * und;
    const float gf3 = a3 * und;

    // channels: 0 = gf, 1 = gf + und, 2 = relu(gf - und)
    const float c00 = gf0, c01 = gf1, c02 = gf2, c03 = gf3;
    const float c10 = gf0 + und, c11 = gf1 + und, c12 = gf2 + und, c13 = gf3 + und;
    const float c20 = fmaxf(gf0 - und, 0.0f);
    const float c21 = fmaxf(gf1 - und, 0.0f);
    const float c22 = fmaxf(gf2 - und, 0.0f);
    const float c23 = fmaxf(gf3 - und, 0.0f);

    const float p_last = c20 * c21 * c22 * c23;
    const float cf_last = lf * sqrtf(sqrtf(p_last));

    for (int c = lane; c < NCOMBO; c += 64) {
        const int i = c / 27;
        const int j = (c / 9) % 3;
        const int kk = (c / 3) % 3;
        const int l = c % 3;
        const float p = pick3(i, c00, c10, c20) *
                        pick3(j, c01, c11, c21) *
                        pick3(kk, c02, c12, c22) *
                        pick3(l, c03, c13, c23);
        const float cf = lf * sqrtf(sqrtf(p));
        o_slist[(size_t)b * NCOMBO + c] = cf - cf_last;
        if (c == 0) o_score[b] = cf;
    }

    if (lane == 0) {
        const float base = gf0 * gf1 * gf2 * gf3;
        // JAX max-tie gradient: w = 1 if r>1, 0.5 if r==1, 0 if r<1
        const float w = (r > 1.0f) ? 1.0f : ((r == 1.0f) ? 0.5f : 0.0f);
        o_sdl[b] = sqrtf(sqrtf(base)) * lf * w * (l_r + FEPS) / (li_e * li_e);
    }
}

extern "C" void kernel_launch(void* const* d_in, const int* in_sizes, int n_in,
                              void* d_out, int out_size, void* d_ws, size_t ws_size,
                              hipStream_t stream) {
    const float* tc_res = (const float*)d_in[0];
    const float* tc_gts = (const float*)d_in[1];
    const float* l_res  = (const float*)d_in[2];
    const float* l_gts  = (const float*)d_in[3];
    const int B = in_sizes[2];   // l_res has B elements

    float* out = (float*)d_out;
    float* o_score = out;
    float* o_slist = o_score + B;
    float* o_judge = o_slist + (size_t)B * NCOMBO;
    float* o_sdl   = o_judge + (size_t)B * NKDIM;

    const int waves_per_block = 4;             // 256 threads
    const int blocks = (B + waves_per_block - 1) / waves_per_block;
    bleu_kernel<<<blocks, 256, 0, stream>>>(tc_res, tc_gts, l_res, l_gts,
                                            o_score, o_slist, o_judge, o_sdl, B);
}